// Round 6
// baseline (403.362 us; speedup 1.0000x reference)
//
#include <hip/hip_runtime.h>
#include <math.h>

// CTC loss, T=1024 B=64 V=256 L=256 (S=513).
// One WAVE per batch element, zero barriers. 64-thread blocks so the compiler
// register-allocates for a single wave (round 5's 256-thread structure spilled
// the prefetch ring to scratch: VGPR_Count=36, WRITE_SIZE 546 KB).
//  - lane l holds states 8l..8l+7 in registers; state 512 rides on lane 63.
//    Cross-lane dependency = one __shfl_up per step.
//  - LINEAR-domain recursion on RAW logits (softmax denominator deferred: it is
//    a per-(t,b) additive constant in log space -> factors out; cumlse[b]
//    computed by the lse blocks, massively parallel).
//  - e-row pipeline: 4-deep float4 register ring (16 VGPRs; rows are L3-warm
//    because the lse waves stream the whole tensor early) -> ds_write_b128 into
//    a ping-pong LDS row -> 5 raw-value gathers for step t+1 issued at step t,
//    consumed next iteration (same-wave DS is in-order; no barriers anywhere).
//  - INLINE renorm every 8 steps (round 5's deferred renorm + 2^-16 downshift
//    sagged the working range and flushed readout states -> absmax 32).
//    Truncation masks (states >= S_b) applied only at renorm: invalid states
//    are fed from valid ones but never feed back, and can't overflow in 8
//    steps; zeroing them each window keeps them out of the max.
//  - loss_b = cumlse[b] - ( ln(a[end]+a[end-1]) + ln2*log2acc )

constexpr int V = 256;
constexpr float LN2_F = 0.6931471805599453f;

__global__ __launch_bounds__(64) void ctc_main(
    const int*   __restrict__ labels,      // [B, L]
    const float* __restrict__ logits,      // [T, B, V]
    const int*   __restrict__ label_len,   // [B]
    const int*   __restrict__ logit_len,   // [B]
    float*       __restrict__ cumlse,      // [B] (pre-zeroed, atomicAdd)
    float*       __restrict__ lnterm,      // [B]
    int T, int B, int L)
{
    const int l = threadIdx.x;             // lane == thread (64-thread block)

    if ((int)blockIdx.x < B) {
        // ================= recursion block: one wave, one batch ===============
        const int b = blockIdx.x;
        __shared__ float erow[2][V];       // raw logit row, ping-pong
        __shared__ float afin[514];        // final alpha for readout

        const int Tb = logit_len[b];
        const int Lb = label_len[b];
        const int Sb = 2 * Lb + 1;

        const float* lg = logits + (size_t)b * V;
        const size_t rs = (size_t)B * V;

        // odd states 8l+1,3,5,7 emit labels[4l+0..3]
        const int4 lb4 = ((const int4*)(labels + (size_t)b * L))[l];
        const int prevw = __shfl_up(lb4.w, 1);           // labels[4l-1]
        const float sk1 = (l > 0 && lb4.x != prevw) ? 1.f : 0.f;
        const float sk3 = (lb4.y != lb4.x) ? 1.f : 0.f;
        const float sk5 = (lb4.z != lb4.y) ? 1.f : 0.f;
        const float sk7 = (lb4.w != lb4.z) ? 1.f : 0.f;

        float mk[8];
        #pragma unroll
        for (int j = 0; j < 8; ++j) mk[j] = (8 * l + j < Sb) ? 1.f : 0.f;
        const float mk512 = (Sb > 512 && l == 63) ? 1.f : 0.f;

        // t=0 init: states 0,1 only
        float cur[8], cur2 = 0.f;
        #pragma unroll
        for (int j = 0; j < 8; ++j) cur[j] = 0.f;
        if (l == 0) {
            cur[0] = __expf(lg[0]);
            cur[1] = __expf(lg[lb4.x]);
        }

        // prologue: stage row 1, gather raw values for t=1
        float geb = 0.f, g1 = 0.f, g3 = 0.f, g5 = 0.f, g7 = 0.f;
        if (Tb >= 2) {
            ((float4*)erow[1])[l] = ((const float4*)(lg + rs))[l];
            geb = erow[1][0];
            g1 = erow[1][lb4.x]; g3 = erow[1][lb4.y];
            g5 = erow[1][lb4.z]; g7 = erow[1][lb4.w];
        }
        // ring: row r lives in rp[r&3]; prefill rows 2..5 (clamped)
        float4 rp[4];
        #pragma unroll
        for (int j = 2; j <= 5; ++j) {
            const int r = (j < Tb) ? j : (Tb - 1);
            rp[j & 3] = ((const float4*)(lg + rs * r))[l];
        }

        float log2acc = 0.f;
        for (int tb = 0; tb * 8 < Tb; ++tb) {
            #pragma unroll
            for (int u = 0; u < 8; ++u) {
                const int t = 8 * tb + u;
                if (t >= Tb) break;
                if (t == 0) continue;      // t=0 handled by init/prologue
                // ---- stage row t+1; gathers for t+1; refill ring (row t+5) --
                const int slot = (u + 1) & 3;          // == (t+1)&3
                float* er = erow[(t + 1) & 1];
                ((float4*)er)[l] = rp[slot];
                int rn = t + 5; if (rn > Tb - 1) rn = Tb - 1;
                rp[slot] = ((const float4*)(lg + rs * rn))[l];
                const float ngb = er[0];
                const float n1 = er[lb4.x], n3 = er[lb4.y];
                const float n5 = er[lb4.z], n7 = er[lb4.w];
                // ---- consume step-t e-values (gathered last iteration) ------
                const float xb = __expf(geb);
                const float x1 = __expf(g1), x3 = __expf(g3);
                const float x5 = __expf(g5), x7 = __expf(g7);
                float c7m = __shfl_up(cur[7], 1);
                if (l == 0) c7m = 0.f;
                // descending update: each line uses OLD lower-indexed values
                cur2   = (cur2 + cur[7]) * xb;                    // state 512
                cur[7] = fmaf(sk7, cur[5], cur[7] + cur[6]) * x7;
                cur[6] = (cur[6] + cur[5]) * xb;
                cur[5] = fmaf(sk5, cur[3], cur[5] + cur[4]) * x5;
                cur[4] = (cur[4] + cur[3]) * xb;
                cur[3] = fmaf(sk3, cur[1], cur[3] + cur[2]) * x3;
                cur[2] = (cur[2] + cur[1]) * xb;
                cur[1] = fmaf(sk1, c7m, cur[1] + cur[0]) * x1;
                cur[0] = (cur[0] + c7m) * xb;
                // ---- inline renorm every 8 steps (mask, max, scale) ---------
                if (u == 7) {
                    cur2 *= mk512;
                    #pragma unroll
                    for (int j = 0; j < 8; ++j) cur[j] *= mk[j];
                    float m = cur2;
                    #pragma unroll
                    for (int j = 0; j < 8; ++j) m = fmaxf(m, cur[j]);
                    #pragma unroll
                    for (int o = 1; o <= 32; o <<= 1)
                        m = fmaxf(m, __shfl_xor(m, o, 64));
                    const float M   = fmaxf(m, 1e-30f);
                    const float inv = 1.f / M;
                    cur2 *= inv;
                    #pragma unroll
                    for (int j = 0; j < 8; ++j) cur[j] *= inv;
                    log2acc += log2f(M);
                }
                geb = ngb; g1 = n1; g3 = n3; g5 = n5; g7 = n7;
            }
        }

        // ---- readout: ln(a[end]+a[end-1]) + ln2*log2acc ----
        #pragma unroll
        for (int j = 0; j < 8; ++j) afin[8 * l + j] = cur[j];
        if (l == 63) afin[512] = cur2;
        const int end = 2 * Lb;
        const int em1 = (end > 0) ? end - 1 : 0;
        float ssum = afin[end] + afin[em1];      // same-wave DS, in-order
        ssum = fmaxf(ssum, 1e-37f);              // inf-protection only
        if (l == 0) lnterm[b] = logf(ssum) + LN2_F * log2acc;
    } else {
        // ============ lse wave-blocks: cumlse[b] += lse(logits[t,b,:]) =======
        const int w  = blockIdx.x - B;
        const int nW = gridDim.x - B;            // 1024 waves, 64 rows each
        const int rows = T * B;
        float acc = 0.f;
        int   cb  = -1;
        int r = w;
        if (r >= rows) return;
        float4 nxt = ((const float4*)(logits + (size_t)r * V))[l];
        while (true) {
            const int rn = r + nW;
            const bool more = rn < rows;
            const float4 x = nxt;
            if (more) nxt = ((const float4*)(logits + (size_t)rn * V))[l];
            float m = fmaxf(fmaxf(x.x, x.y), fmaxf(x.z, x.w));
            #pragma unroll
            for (int o = 32; o >= 1; o >>= 1) m = fmaxf(m, __shfl_xor(m, o, 64));
            float ss = __expf(x.x - m) + __expf(x.y - m) +
                       __expf(x.z - m) + __expf(x.w - m);
            #pragma unroll
            for (int o = 32; o >= 1; o >>= 1) ss += __shfl_xor(ss, o, 64);
            const int t  = r / B;
            const int bb = r - t * B;
            if (bb != cb) {                      // nW % B == 0 -> constant bb
                if (l == 0 && cb >= 0) atomicAdd(&cumlse[cb], acc);
                acc = 0.f;
                cb  = bb;
            }
            if (t < logit_len[bb]) acc += m + logf(ss);
            if (!more) break;
            r = rn;
        }
        if (l == 0 && cb >= 0) atomicAdd(&cumlse[cb], acc);
    }
}

__global__ __launch_bounds__(64) void ctc_final(
    const float* __restrict__ cumlse,
    const float* __restrict__ lnterm,
    float* __restrict__ out, int B)
{
    const int b = threadIdx.x;
    float v = (b < B) ? (cumlse[b] - lnterm[b]) : 0.f;
    #pragma unroll
    for (int o = 32; o >= 1; o >>= 1) v += __shfl_xor(v, o, 64);
    if (threadIdx.x == 0) out[0] = v / (float)B;
}

extern "C" void kernel_launch(void* const* d_in, const int* in_sizes, int n_in,
                              void* d_out, int out_size, void* d_ws, size_t ws_size,
                              hipStream_t stream) {
    const int*   labels    = (const int*)d_in[0];
    const float* logits    = (const float*)d_in[1];
    const int*   label_len = (const int*)d_in[2];
    const int*   logit_len = (const int*)d_in[3];

    const int B = in_sizes[2];                 // 64
    const int L = in_sizes[0] / B;             // 256
    const int T = in_sizes[1] / (B * V);       // 1024

    float* cumlse = (float*)d_ws;              // [B]
    float* lnterm = cumlse + B;                // [B]

    hipMemsetAsync(cumlse, 0, B * sizeof(float), stream);

    const int nLse = 1024;                     // 1024 lse waves -> 64 rows each
    ctc_main<<<B + nLse, 64, 0, stream>>>(labels, logits, label_len, logit_len,
                                          cumlse, lnterm, T, B, L);
    ctc_final<<<1, 64, 0, stream>>>(cumlse, lnterm, (float*)d_out, B);
}

// Round 7
// 229.019 us; speedup vs baseline: 1.7613x; 1.7613x over previous
//
#include <hip/hip_runtime.h>
#include <math.h>

// CTC loss, T=1024 B=64 V=256 L=256 (S=513).
// One WAVE per batch element, zero barriers, fully-static register pipeline.
// Rounds 5/6 post-mortem: rp[runtime_idx] forced the prefetch ring into
// SCRATCH (dynamically-indexed arrays can't live in VGPRs) -> VGPR_Count 32,
// ~775 cyc/step. This version hand-unrolls 16-step windows with LITERAL ring
// slots and gather-set names so everything register-allocates.
//  - lane l holds states 8l..8l+7; state 512 rides every lane's curT but is
//    only valid (and masked/read) on lane 63. Cross-lane dep = 1 shfl_up/step.
//  - LINEAR-domain recursion on RAW logits (softmax denominator deferred;
//    cumlse computed by lse waves in parallel).
//  - Pipeline at step t: consume gather-set g[t&3] (EXP'D row-t values);
//    stage row t+2 (4 exps on ring regs -> ds_write_b128 -> 5 gathers into
//    g[(t+2)&3]); refill ring slot (t+2)&3 with row t+6. 2-step DS slack,
//    4-step global slack, no vmcnt(0)/lgkmcnt(0) drains anywhere.
//  - Renorm every 16 steps (worst-case growth ~2^106 < 2^127); accounting
//    uses the APPLIED multiplier: log2acc -= log2f(inv).
//  - lse: wave w owns b=w%64 (rows r=w+1024k), writes partial[w]; no atomics,
//    no memset. ctc_final: thread b sums partial[b+64k] - lnterm[b], mean.

constexpr int V = 256;
constexpr float LN2_F = 0.6931471805599453f;

#define MACS(EB, E1, E3, E5, E7) do {                                  \
    float c7m = __shfl_up(cur7, 1); c7m = (l == 0) ? 0.f : c7m;        \
    curT = (curT + cur7) * (EB);                                       \
    cur7 = fmaf(sk7, cur5, cur7 + cur6) * (E7);                        \
    cur6 = (cur6 + cur5) * (EB);                                       \
    cur5 = fmaf(sk5, cur3, cur5 + cur4) * (E5);                        \
    cur4 = (cur4 + cur3) * (EB);                                       \
    cur3 = fmaf(sk3, cur1, cur3 + cur2) * (E3);                        \
    cur2 = (cur2 + cur1) * (EB);                                       \
    cur1 = fmaf(sk1, c7m, cur1 + cur0) * (E1);                         \
    cur0 = (cur0 + c7m) * (EB);                                        \
  } while (0)

// exp the ring regs, write exp'd row to LDS, gather 5 values into set GS
#define STAGE_GATHER(GS, XV) do {                                      \
    float4 _e;                                                         \
    _e.x = __expf((XV).x); _e.y = __expf((XV).y);                      \
    _e.z = __expf((XV).z); _e.w = __expf((XV).w);                      \
    ((float4*)erow)[l] = _e;                                           \
    GS##b = erow[0];  GS##p = erow[ix]; GS##q = erow[iy];              \
    GS##r = erow[iz]; GS##s = erow[iw];                                \
  } while (0)

// one time step: TT = t (expression), GC/GS = gather-set name tokens,
// SL = literal ring slot == (t+2)&3
#define STEP(TT, GC, GS, SL) do {                                      \
    MACS(GC##b, GC##p, GC##q, GC##r, GC##s);                           \
    float4 _x = rp##SL;                                                \
    STAGE_GATHER(GS, _x);                                              \
    int _rn = (TT) + 6; if (_rn > Tbm1) _rn = Tbm1;                    \
    rp##SL = *(const float4*)(lg + rs * (size_t)_rn + 4 * l);          \
  } while (0)

#define RENORM do {                                                    \
    curT *= mkT; cur0 *= mk0; cur1 *= mk1; cur2 *= mk2; cur3 *= mk3;   \
    cur4 *= mk4; cur5 *= mk5; cur6 *= mk6; cur7 *= mk7;                \
    float _m = fmaxf(curT, cur0); _m = fmaxf(_m, cur1);                \
    _m = fmaxf(_m, cur2); _m = fmaxf(_m, cur3); _m = fmaxf(_m, cur4);  \
    _m = fmaxf(_m, cur5); _m = fmaxf(_m, cur6); _m = fmaxf(_m, cur7);  \
    _m = fmaxf(_m, __shfl_xor(_m, 1, 64));                             \
    _m = fmaxf(_m, __shfl_xor(_m, 2, 64));                             \
    _m = fmaxf(_m, __shfl_xor(_m, 4, 64));                             \
    _m = fmaxf(_m, __shfl_xor(_m, 8, 64));                             \
    _m = fmaxf(_m, __shfl_xor(_m, 16, 64));                            \
    _m = fmaxf(_m, __shfl_xor(_m, 32, 64));                            \
    const float _inv = 1.f / fmaxf(_m, 1e-30f);                        \
    log2acc -= log2f(_inv);                                            \
    curT *= _inv; cur0 *= _inv; cur1 *= _inv; cur2 *= _inv;            \
    cur3 *= _inv; cur4 *= _inv; cur5 *= _inv; cur6 *= _inv;            \
    cur7 *= _inv;                                                      \
  } while (0)

__global__ __launch_bounds__(64) void ctc_main(
    const int*   __restrict__ labels,      // [B, L]
    const float* __restrict__ logits,      // [T, B, V]
    const int*   __restrict__ label_len,   // [B]
    const int*   __restrict__ logit_len,   // [B]
    float*       __restrict__ partial,     // [nLse] per-wave lse sums
    float*       __restrict__ lnterm,      // [B]
    int T, int B, int L)
{
    const int l = threadIdx.x;             // lane == thread

    if ((int)blockIdx.x < B) {
        // =============== recursion: one wave, one batch element ==============
        const int b = blockIdx.x;
        __shared__ float erow[V];          // exp'd logit row (single buffer:
                                           // same-wave DS ops are in-order)
        __shared__ float afin[514];        // final alpha for readout

        const int Tb = logit_len[b];
        const int Lb = label_len[b];
        const int Sb = 2 * Lb + 1;
        const int Tbm1 = Tb - 1;

        const float* lg = logits + (size_t)b * V;
        const size_t rs = (size_t)B * V;

        const int4 lb4 = ((const int4*)(labels + (size_t)b * L))[l];
        const int ix = lb4.x, iy = lb4.y, iz = lb4.z, iw = lb4.w;
        const int prevw = __shfl_up(iw, 1);              // labels[4l-1]
        const float sk1 = (l > 0 && ix != prevw) ? 1.f : 0.f;
        const float sk3 = (iy != ix) ? 1.f : 0.f;
        const float sk5 = (iz != iy) ? 1.f : 0.f;
        const float sk7 = (iw != iz) ? 1.f : 0.f;

        const float mk0 = (8 * l + 0 < Sb) ? 1.f : 0.f;
        const float mk1 = (8 * l + 1 < Sb) ? 1.f : 0.f;
        const float mk2 = (8 * l + 2 < Sb) ? 1.f : 0.f;
        const float mk3 = (8 * l + 3 < Sb) ? 1.f : 0.f;
        const float mk4 = (8 * l + 4 < Sb) ? 1.f : 0.f;
        const float mk5 = (8 * l + 5 < Sb) ? 1.f : 0.f;
        const float mk6 = (8 * l + 6 < Sb) ? 1.f : 0.f;
        const float mk7 = (8 * l + 7 < Sb) ? 1.f : 0.f;
        const float mkT = (Sb > 512 && l == 63) ? 1.f : 0.f;

        // t=0 init: states 0,1 only
        float cur0 = 0.f, cur1 = 0.f, cur2 = 0.f, cur3 = 0.f;
        float cur4 = 0.f, cur5 = 0.f, cur6 = 0.f, cur7 = 0.f, curT = 0.f;
        if (l == 0) {
            cur0 = __expf(lg[0]);
            cur1 = __expf(lg[ix]) * mk1;
        }

        // gather sets (5 regs each): g<k> holds exp'd row values, row ≡ k mod 4
        float g0b = 0, g0p = 0, g0q = 0, g0r = 0, g0s = 0;
        float g1b = 0, g1p = 0, g1q = 0, g1r = 0, g1s = 0;
        float g2b = 0, g2p = 0, g2q = 0, g2r = 0, g2s = 0;
        float g3b = 0, g3p = 0, g3q = 0, g3r = 0, g3s = 0;

        // prologue: stage rows 1,2 -> g1,g2
        {
            int r = (1 < Tbm1) ? 1 : Tbm1;
            float4 x = *(const float4*)(lg + rs * (size_t)r + 4 * l);
            STAGE_GATHER(g1, x);
            r = (2 < Tbm1) ? 2 : Tbm1;
            x = *(const float4*)(lg + rs * (size_t)r + 4 * l);
            STAGE_GATHER(g2, x);
        }
        // ring prefill: rp<k> = row k+3 pattern -> rp3=row3, rp0=4, rp1=5, rp2=6
        float4 rp0, rp1, rp2, rp3;
        {
            int r3 = (3 < Tbm1) ? 3 : Tbm1, r4 = (4 < Tbm1) ? 4 : Tbm1;
            int r5 = (5 < Tbm1) ? 5 : Tbm1, r6 = (6 < Tbm1) ? 6 : Tbm1;
            rp3 = *(const float4*)(lg + rs * (size_t)r3 + 4 * l);
            rp0 = *(const float4*)(lg + rs * (size_t)r4 + 4 * l);
            rp1 = *(const float4*)(lg + rs * (size_t)r5 + 4 * l);
            rp2 = *(const float4*)(lg + rs * (size_t)r6 + 4 * l);
        }

        float log2acc = 0.f;
        int base = 1;
        if (Tb >= 16) {
            // first window: t = 1..15
            STEP(1,  g1, g3, 3);  STEP(2,  g2, g0, 0);
            STEP(3,  g3, g1, 1);  STEP(4,  g0, g2, 2);
            STEP(5,  g1, g3, 3);  STEP(6,  g2, g0, 0);
            STEP(7,  g3, g1, 1);  STEP(8,  g0, g2, 2);
            STEP(9,  g1, g3, 3);  STEP(10, g2, g0, 0);
            STEP(11, g3, g1, 1);  STEP(12, g0, g2, 2);
            STEP(13, g1, g3, 3);  STEP(14, g2, g0, 0);
            STEP(15, g3, g1, 1);
            RENORM;
            // main windows: base ≡ 0 mod 16
            for (base = 16; base + 16 <= Tb; base += 16) {
                STEP(base + 0,  g0, g2, 2);  STEP(base + 1,  g1, g3, 3);
                STEP(base + 2,  g2, g0, 0);  STEP(base + 3,  g3, g1, 1);
                STEP(base + 4,  g0, g2, 2);  STEP(base + 5,  g1, g3, 3);
                STEP(base + 6,  g2, g0, 0);  STEP(base + 7,  g3, g1, 1);
                STEP(base + 8,  g0, g2, 2);  STEP(base + 9,  g1, g3, 3);
                STEP(base + 10, g2, g0, 0);  STEP(base + 11, g3, g1, 1);
                STEP(base + 12, g0, g2, 2);  STEP(base + 13, g1, g3, 3);
                STEP(base + 14, g2, g0, 0);  STEP(base + 15, g3, g1, 1);
                RENORM;
            }
        }
        // scalar tail (t = base..Tb-1): direct global gathers; <=15 steps of
        // growth cannot overflow, and readout never touches garbage states.
        for (int t = base; t < Tb; ++t) {
            const float* rowp = lg + rs * (size_t)t;
            const float eb = __expf(rowp[0]);
            const float e1 = __expf(rowp[ix]), e3 = __expf(rowp[iy]);
            const float e5 = __expf(rowp[iz]), e7 = __expf(rowp[iw]);
            MACS(eb, e1, e3, e5, e7);
        }

        // readout: ln(a[end] + a[end-1]) + ln2*log2acc
        afin[8 * l + 0] = cur0; afin[8 * l + 1] = cur1;
        afin[8 * l + 2] = cur2; afin[8 * l + 3] = cur3;
        afin[8 * l + 4] = cur4; afin[8 * l + 5] = cur5;
        afin[8 * l + 6] = cur6; afin[8 * l + 7] = cur7;
        if (l == 63) afin[512] = curT;
        const int end = 2 * Lb;
        const int em1 = (end > 0) ? end - 1 : 0;
        float ssum = afin[end] + afin[em1];     // same-wave DS, in-order
        ssum = fmaxf(ssum, 1e-37f);             // inf-protection only
        if (l == 0) lnterm[b] = logf(ssum) + LN2_F * log2acc;
    } else {
        // ====== lse waves: partial[w] = sum of lse over rows r ≡ w (mod nW) ==
        const int w  = blockIdx.x - B;          // 0..nW-1
        const int nW = gridDim.x - B;
        const int rows = T * B;
        const int bb = w % B;                   // constant per wave
        const int Tbb = logit_len[bb];
        float acc = 0.f;
        int r = w;
        if (r < rows) {
            float4 nxt = ((const float4*)(logits + (size_t)r * V))[l];
            while (true) {
                const int rn = r + nW;
                const bool more = rn < rows;
                const float4 x = nxt;
                if (more) nxt = ((const float4*)(logits + (size_t)rn * V))[l];
                float m = fmaxf(fmaxf(x.x, x.y), fmaxf(x.z, x.w));
                #pragma unroll
                for (int o = 32; o >= 1; o >>= 1)
                    m = fmaxf(m, __shfl_xor(m, o, 64));
                float ss = __expf(x.x - m) + __expf(x.y - m) +
                           __expf(x.z - m) + __expf(x.w - m);
                #pragma unroll
                for (int o = 32; o >= 1; o >>= 1) ss += __shfl_xor(ss, o, 64);
                const int t = r / B;
                if (t < Tbb) acc += m + logf(ss);
                if (!more) break;
                r = rn;
            }
        }
        if (l == 0) partial[w] = acc;
    }
}

__global__ __launch_bounds__(64) void ctc_final(
    const float* __restrict__ partial,     // [nW]
    const float* __restrict__ lnterm,      // [B]
    float* __restrict__ out, int B, int nW)
{
    const int b = threadIdx.x;
    float v = 0.f;
    if (b < B) {
        float c = 0.f;
        for (int k = b; k < nW; k += B) c += partial[k];
        v = c - lnterm[b];
    }
    #pragma unroll
    for (int o = 32; o >= 1; o >>= 1) v += __shfl_xor(v, o, 64);
    if (threadIdx.x == 0) out[0] = v / (float)B;
}

extern "C" void kernel_launch(void* const* d_in, const int* in_sizes, int n_in,
                              void* d_out, int out_size, void* d_ws, size_t ws_size,
                              hipStream_t stream) {
    const int*   labels    = (const int*)d_in[0];
    const float* logits    = (const float*)d_in[1];
    const int*   label_len = (const int*)d_in[2];
    const int*   logit_len = (const int*)d_in[3];

    const int B = in_sizes[2];                 // 64
    const int L = in_sizes[0] / B;             // 256
    const int T = in_sizes[1] / (B * V);       // 1024

    const int nLse = 1024;                     // 64 rows per lse wave
    float* partial = (float*)d_ws;             // [nLse]
    float* lnterm  = partial + nLse;           // [B]

    ctc_main<<<B + nLse, 64, 0, stream>>>(labels, logits, label_len, logit_len,
                                          partial, lnterm, T, B, L);
    ctc_final<<<1, 64, 0, stream>>>(partial, lnterm, (float*)d_out, B, nLse);
}